// Round 12
// baseline (324.928 us; speedup 1.0000x reference)
//
#include <hip/hip_runtime.h>
#include <hip/hip_fp16.h>
#include <math.h>

#define NN 10000      // nodes
#define NE 320000     // edges
#define NG 64         // graphs
#define DD 256        // feature dim (in == hid)
#define DOUT 16
#define SLOT 96       // padded CSR slots per node

typedef __attribute__((ext_vector_type(8))) _Float16 f16x8;
typedef __attribute__((ext_vector_type(4))) float f32x4;

// ---- workspace layout (bytes) ----
#define OFF_CNT   0u            // NN ints
#define OFF_CSR   40064u        // NN*SLOT ints
#define OFF_XH    3880064u      // NN*DD f16
#define OFF_AGGR  9000064u      // NN*DD f16 (also pool-dummy region in R12)
#define OFF_H1    14120064u     // NN*DD f16
#define OFF_H2    19240064u     // NN*DD f16 (also fill-dummy csr region in R12)
#define OFF_WH    24360064u     // 4 * 65536 f16
#define OFF_POOL  24884352u     // NG*DD fp32
#define OFF_DCNT  24950016u     // 7 * NN ints (R12 probe dummy counters)

__device__ __forceinline__ void gload16(const void* g, void* l) {
  __builtin_amdgcn_global_load_lds(
      (const __attribute__((address_space(1))) void*)g,
      (__attribute__((address_space(3))) void*)l, 16, 0, 0);
}

// ---------- init: zero cnt + pooled + probe dummy counters ----------
__global__ __launch_bounds__(256) void init_kernel(int* __restrict__ cnt,
                                                   float* __restrict__ pooled,
                                                   int* __restrict__ dcnt) {
  int i = blockIdx.x * 256 + threadIdx.x;   // 64 blocks
  if (i < NN) {
    cnt[i] = 0;
#pragma unroll
    for (int r = 0; r < 7; ++r) dcnt[r * NN + i] = 0;
  }
  if (i < NG * DD) pooled[i] = 0.f;
}

// ---------- CSR fill (R12: mega x8; rep 0 real, 1-7 dummy) ----------
#define NFB 1250
__global__ __launch_bounds__(256) void fill_kernel(const int* __restrict__ ei,
                                                   int* __restrict__ cnt,
                                                   int* __restrict__ csr,
                                                   int* __restrict__ dcnt,
                                                   int* __restrict__ dcsr) {
  int e = blockIdx.x * 256 + threadIdx.x;   // 1250*256 == NE
  int rep = blockIdx.y;
  int* C = (rep == 0) ? cnt : dcnt + (rep - 1) * NN;
  int* R = (rep == 0) ? csr : dcsr;
  int s = ei[e];
  int d = ei[NE + e];
  int p = atomicAdd(&C[d], 1);
  if (p < SLOT) R[d * SLOT + p] = s;
}

// ---------- fp32->fp16 casts (R12: mega x8, idempotent) ----------
#define NXG (NN * DD / 8)
#define NWG 8192
#define NCB2 ((NXG + 4 * NWG + 255) / 256)
__global__ __launch_bounds__(256) void cast_kernel(
    const float* __restrict__ x, const float* __restrict__ w1l,
    const float* __restrict__ w1r, const float* __restrict__ w2l,
    const float* __restrict__ w2r, _Float16* __restrict__ xh,
    _Float16* __restrict__ wh) {
  int i = blockIdx.x * 256 + threadIdx.x;
  const float* src;
  _Float16* dst;
  if (i < NXG) {
    src = x + i * 8;
    dst = xh + i * 8;
  } else if (i < NXG + 4 * NWG) {
    int j = i - NXG;
    int w = j >> 13, k = j & (NWG - 1);
    src = ((w == 0) ? w1l : (w == 1) ? w1r : (w == 2) ? w2l : w2r) + k * 8;
    dst = wh + w * 65536 + k * 8;
  } else {
    return;
  }
  const float4* sp = (const float4*)src;
  float4 a = sp[0], b = sp[1];
  f16x8 r;
  r[0] = (_Float16)a.x; r[1] = (_Float16)a.y; r[2] = (_Float16)a.z; r[3] = (_Float16)a.w;
  r[4] = (_Float16)b.x; r[5] = (_Float16)b.y; r[6] = (_Float16)b.z; r[7] = (_Float16)b.w;
  *(f16x8*)dst = r;
}

// ---------- mean aggregation: one wave per node, 8x unrolled ----------
__global__ __launch_bounds__(256) void aggregate_f16_kernel(
    const _Float16* __restrict__ xin, const int* __restrict__ cnt,
    const int* __restrict__ csr, _Float16* __restrict__ out) {
  const int wave = threadIdx.x >> 6, lane = threadIdx.x & 63;
  const int node = blockIdx.x * 4 + wave;
  if (node >= NN) return;
  const int deg = cnt[node];
  const int n = min(deg, SLOT);
  const int base = node * SLOT;
  const int h = lane >> 5;
  const int cb = (lane & 31) * 8;
  float a[8] = {0.f, 0.f, 0.f, 0.f, 0.f, 0.f, 0.f, 0.f};
  int i = h;
  for (; i + 14 < n; i += 16) {
    f16x8 v[8];
#pragma unroll
    for (int u = 0; u < 8; ++u) {
      int s = csr[base + i + 2 * u];
      v[u] = *(const f16x8*)&xin[s * DD + cb];
    }
#pragma unroll
    for (int j = 0; j < 8; ++j)
      a[j] += (((float)v[0][j] + (float)v[1][j]) + ((float)v[2][j] + (float)v[3][j])) +
              (((float)v[4][j] + (float)v[5][j]) + ((float)v[6][j] + (float)v[7][j]));
  }
  for (; i < n; i += 2) {
    int s = csr[base + i];
    f16x8 v = *(const f16x8*)&xin[s * DD + cb];
#pragma unroll
    for (int j = 0; j < 8; ++j) a[j] += (float)v[j];
  }
#pragma unroll
  for (int j = 0; j < 8; ++j) a[j] += __shfl_xor(a[j], 32);
  if (lane < 32) {
    float inv = 1.0f / fmaxf((float)deg, 1.0f);
    f16x8 r;
#pragma unroll
    for (int j = 0; j < 8; ++j) r[j] = (_Float16)(a[j] * inv);
    *(f16x8*)&out[node * DD + cb] = r;
  }
}

// ---------- fused SAGE GEMM via MFMA (R12: gemm2 mega x8 via blockIdx.y) ----------
__global__ __launch_bounds__(256) void gemm_mfma_kernel(
    const _Float16* __restrict__ A1, const _Float16* __restrict__ A2,
    const _Float16* __restrict__ W1, const _Float16* __restrict__ W2,
    const float* __restrict__ bias, _Float16* __restrict__ out) {
  __shared__ _Float16 As[2][128 * 64];
  __shared__ _Float16 Bs[2][64 * 64];
  const int id = blockIdx.x;
  const int xcd = id & 7;
  const int q = id >> 3;
  const int cblk = q & 3;
  const int rblk = (q >> 2) * 8 + xcd;
  const int row0 = rblk * 128, col0 = cblk * 64;
  if (row0 >= NN) return;

  const int t = threadIdx.x;
  const int lane = t & 63;
  const int wid = t >> 6;
  const int wr = wid >> 1, wc = wid & 1;
  const int fr = lane & 15;
  const int fg = lane >> 4;
  const int srl = lane >> 3;
  const int cj = lane & 7;

  f32x4 acc[4][2];
#pragma unroll
  for (int m = 0; m < 4; ++m)
#pragma unroll
    for (int n = 0; n < 2; ++n) {
      acc[m][n][0] = 0.f; acc[m][n][1] = 0.f;
      acc[m][n][2] = 0.f; acc[m][n][3] = 0.f;
    }

#define STAGE(B, S)                                                           \
  {                                                                           \
    const _Float16* Ap = ((S) < 4) ? A1 : A2;                                 \
    const _Float16* Wp = ((S) < 4) ? W1 : W2;                                 \
    const int k0 = ((S) & 3) * 64;                                            \
    _Pragma("unroll") for (int j = 0; j < 4; ++j) {                           \
      int row = (wid * 4 + j) * 8 + srl;                                      \
      int gr = row0 + row; if (gr >= NN) gr = NN - 1;                         \
      int gc = cj ^ (row & 7);                                                \
      gload16(Ap + (size_t)gr * DD + k0 + gc * 8, &As[B][(wid * 4 + j) * 512]);\
    }                                                                         \
    _Pragma("unroll") for (int j = 0; j < 2; ++j) {                           \
      int row = (wid * 2 + j) * 8 + srl;                                      \
      int gc = cj ^ (row & 7);                                                \
      gload16(Wp + (size_t)(col0 + row) * DD + k0 + gc * 8,                   \
              &Bs[B][(wid * 2 + j) * 512]);                                   \
    }                                                                         \
  }

  STAGE(0, 0);
  __syncthreads();

#pragma unroll
  for (int s = 0; s < 8; ++s) {
    const int b = s & 1;
    if (s < 7) STAGE(1 - b, s + 1);
#pragma unroll
    for (int kk = 0; kk < 2; ++kk) {
      f16x8 af[4], bf[2];
#pragma unroll
      for (int m = 0; m < 4; ++m) {
        int row = wr * 64 + m * 16 + fr;
        int ch = (kk * 4 + fg) ^ (row & 7);
        af[m] = *(const f16x8*)&As[b][row * 64 + ch * 8];
      }
#pragma unroll
      for (int n = 0; n < 2; ++n) {
        int row = wc * 32 + n * 16 + fr;
        int ch = (kk * 4 + fg) ^ (row & 7);
        bf[n] = *(const f16x8*)&Bs[b][row * 64 + ch * 8];
      }
#pragma unroll
      for (int m = 0; m < 4; ++m)
#pragma unroll
        for (int n = 0; n < 2; ++n)
          acc[m][n] = __builtin_amdgcn_mfma_f32_16x16x32_f16(af[m], bf[n], acc[m][n], 0, 0, 0);
    }
    __syncthreads();
  }
#undef STAGE

  const int orow = row0 + wr * 64 + (lane >> 4) * 4;
  const int ocol = col0 + wc * 32 + fr;
#pragma unroll
  for (int m = 0; m < 4; ++m)
#pragma unroll
    for (int n = 0; n < 2; ++n) {
      int col = ocol + n * 16;
      float bv = bias[col];
#pragma unroll
      for (int j = 0; j < 4; ++j) {
        int row = orow + m * 16 + j;
        if (row < NN) {
          float v = acc[m][n][j] + bv;
          out[row * DD + col] = (_Float16)fmaxf(v, 0.f);
        }
      }
    }
}

// ---------- pool (R12: mega x8; rep 0 real, 1-7 dummy into dead aggr) ----------
__global__ __launch_bounds__(256) void pool_chunk_kernel(const _Float16* __restrict__ h2,
                                                         const int* __restrict__ batch,
                                                         float* __restrict__ pooled,
                                                         float* __restrict__ dpool) {
  const int c = threadIdx.x;
  const int n0 = blockIdx.x * 16;
  float* P = (blockIdx.y == 0) ? pooled : dpool + (blockIdx.y - 1) * (NG * DD);
  float acc = 0.f;
  int g = batch[n0];
  for (int i = n0; i < n0 + 16; ++i) {
    int gi = batch[i];
    if (gi != g) {
      atomicAdd(&P[g * DD + c], acc);
      acc = 0.f;
      g = gi;
    }
    acc += (float)h2[i * DD + c];
  }
  atomicAdd(&P[g * DD + c], acc);
}

// ---------- classifier ----------
__global__ __launch_bounds__(256) void cls_kernel(const float* __restrict__ pooled,
                                                  const float* __restrict__ wc,
                                                  const float* __restrict__ bc,
                                                  float* __restrict__ out) {
  int t = blockIdx.x * 256 + threadIdx.x;
  if (t >= NG * DOUT) return;
  int g = t >> 4, j = t & 15;
  float s = bc[j];
  for (int k = 0; k < DD; k += 4) {
    float4 p = *(const float4*)&pooled[g * DD + k];
    float4 w = *(const float4*)&wc[j * DD + k];
    s += p.x * w.x + p.y * w.y + p.z * w.z + p.w * w.w;
  }
  out[t] = 1.0f / (1.0f + expf(-s));
}

extern "C" void kernel_launch(void* const* d_in, const int* in_sizes, int n_in,
                              void* d_out, int out_size, void* d_ws, size_t ws_size,
                              hipStream_t stream) {
  const float* x     = (const float*)d_in[0];
  const int*   ei    = (const int*)d_in[1];
  const int*   batch = (const int*)d_in[2];
  const float* w1_l  = (const float*)d_in[3];
  const float* b1_l  = (const float*)d_in[4];
  const float* w1_r  = (const float*)d_in[5];
  const float* w2_l  = (const float*)d_in[6];
  const float* b2_l  = (const float*)d_in[7];
  const float* w2_r  = (const float*)d_in[8];
  const float* w_cls = (const float*)d_in[9];
  const float* b_cls = (const float*)d_in[10];
  float* out = (float*)d_out;

  char* ws = (char*)d_ws;
  int*       cnt    = (int*)(ws + OFF_CNT);
  int*       csr    = (int*)(ws + OFF_CSR);
  _Float16*  xh     = (_Float16*)(ws + OFF_XH);
  _Float16*  aggr   = (_Float16*)(ws + OFF_AGGR);
  _Float16*  h1     = (_Float16*)(ws + OFF_H1);
  _Float16*  h2     = (_Float16*)(ws + OFF_H2);
  _Float16*  wh     = (_Float16*)(ws + OFF_WH);
  float*     pooled = (float*)(ws + OFF_POOL);
  int*       dcnt   = (int*)(ws + OFF_DCNT);       // 7 dummy counters (probe)
  int*       dcsr   = (int*)(ws + OFF_H2);         // dummy csr in dead h2
  float*     dpool  = (float*)(ws + OFF_AGGR);     // dummy pool in dead aggr

  init_kernel<<<64, 256, 0, stream>>>(cnt, pooled, dcnt);

  // === R12 PROBE: mega-dispatches (grid.y=8) surface in top-5 with PMC ===
  fill_kernel<<<dim3(NFB, 8), 256, 0, stream>>>(ei, cnt, csr, dcnt, dcsr);
  cast_kernel<<<dim3(NCB2, 8), 256, 0, stream>>>(x, w1_l, w1_r, w2_l, w2_r, xh, wh);

  const int agrid = (NN + 3) / 4;

  // layer 1 (gemm1: 5 serial launches -> standalone time from total delta)
  aggregate_f16_kernel<<<agrid, 256, 0, stream>>>(xh, cnt, csr, aggr);
  gemm_mfma_kernel<<<320, 256, 0, stream>>>(aggr, xh, wh, wh + 65536, b1_l, h1);
  gemm_mfma_kernel<<<320, 256, 0, stream>>>(aggr, xh, wh, wh + 65536, b1_l, h1);
  gemm_mfma_kernel<<<320, 256, 0, stream>>>(aggr, xh, wh, wh + 65536, b1_l, h1);
  gemm_mfma_kernel<<<320, 256, 0, stream>>>(aggr, xh, wh, wh + 65536, b1_l, h1);
  gemm_mfma_kernel<<<320, 256, 0, stream>>>(aggr, xh, wh, wh + 65536, b1_l, h1);

  // layer 2 (gemm2: packed mega x8 -> throughput mode + MfmaUtil)
  aggregate_f16_kernel<<<agrid, 256, 0, stream>>>(h1, cnt, csr, aggr);
  gemm_mfma_kernel<<<dim3(320, 8), 256, 0, stream>>>(aggr, h1, wh + 2 * 65536,
                                                     wh + 3 * 65536, b2_l, h2);

  // pool (mega x8) + classifier
  pool_chunk_kernel<<<dim3((NN + 15) / 16, 8), 256, 0, stream>>>(h2, batch, pooled, dpool);
  cls_kernel<<<4, 256, 0, stream>>>(pooled, w_cls, b_cls, out);
}

// Round 13
// 105.756 us; speedup vs baseline: 3.0724x; 3.0724x over previous
//
#include <hip/hip_runtime.h>
#include <hip/hip_fp16.h>
#include <math.h>

#define NN 10000      // nodes
#define NE 320000     // edges
#define NG 64         // graphs
#define DD 256        // feature dim (in == hid)
#define DOUT 16
#define SLOT 96       // padded CSR slots per node

typedef __attribute__((ext_vector_type(8))) _Float16 f16x8;
typedef __attribute__((ext_vector_type(4))) float f32x4;

// ---- workspace layout (bytes, 16B aligned) ----
#define OFF_CNT   0u            // NN ints
#define OFF_CSR   40064u        // NN*SLOT u16 (1.92 MB)
#define OFF_XH    1960064u      // NN*DD f16
#define OFF_AGGR  7080064u      // NN*DD f16
#define OFF_H1    12200064u     // NN*DD f16
#define OFF_H2    17320064u     // NN*DD f16
#define OFF_WH    22440064u     // 4 * 65536 f16
#define OFF_POOL  22964352u     // NG*DD fp32

__device__ __forceinline__ void gload16(const void* g, void* l) {
  __builtin_amdgcn_global_load_lds(
      (const __attribute__((address_space(1))) void*)g,
      (__attribute__((address_space(3))) void*)l, 16, 0, 0);
}

// ---------- init: zero cnt + pooled ----------
__global__ __launch_bounds__(256) void init_kernel(int* __restrict__ cnt,
                                                   float* __restrict__ pooled) {
  int i = blockIdx.x * 256 + threadIdx.x;   // 64 blocks
  if (i < NN) cnt[i] = 0;
  if (i < NG * DD) pooled[i] = 0.f;
}

// ---------- prep: padded-CSR fill (u16) + fp32->fp16 casts ----------
#define NFB 1250                // fill blocks (NE/256)
#define NXG (NN * DD / 8)       // 320000 x-groups of 8
#define NWG 8192                // groups per weight matrix
#define NCB ((NXG + 4 * NWG + 255) / 256)
__global__ __launch_bounds__(256) void prep_kernel(
    const int* __restrict__ ei, int* __restrict__ cnt,
    unsigned short* __restrict__ csr,
    const float* __restrict__ x, const float* __restrict__ w1l,
    const float* __restrict__ w1r, const float* __restrict__ w2l,
    const float* __restrict__ w2r, _Float16* __restrict__ xh,
    _Float16* __restrict__ wh) {
  if (blockIdx.x < NFB) {
    int e = blockIdx.x * 256 + threadIdx.x;
    int s = ei[e];
    int d = ei[NE + e];
    int p = atomicAdd(&cnt[d], 1);
    if (p < SLOT) csr[d * SLOT + p] = (unsigned short)s;  // byte-enabled store
    return;
  }
  int i = (blockIdx.x - NFB) * 256 + threadIdx.x;
  const float* src;
  _Float16* dst;
  if (i < NXG) {
    src = x + i * 8;
    dst = xh + i * 8;
  } else if (i < NXG + 4 * NWG) {
    int j = i - NXG;
    int w = j >> 13, k = j & (NWG - 1);
    src = ((w == 0) ? w1l : (w == 1) ? w1r : (w == 2) ? w2l : w2r) + k * 8;
    dst = wh + w * 65536 + k * 8;
  } else {
    return;
  }
  const float4* sp = (const float4*)src;
  float4 a = sp[0], b = sp[1];
  f16x8 r;
  r[0] = (_Float16)a.x; r[1] = (_Float16)a.y; r[2] = (_Float16)a.z; r[3] = (_Float16)a.w;
  r[4] = (_Float16)b.x; r[5] = (_Float16)b.y; r[6] = (_Float16)b.z; r[7] = (_Float16)b.w;
  *(f16x8*)dst = r;
}

// ---------- mean aggregation: one wave per node, 8x unrolled, u16 indices ----------
__global__ __launch_bounds__(256) void aggregate_f16_kernel(
    const _Float16* __restrict__ xin, const int* __restrict__ cnt,
    const unsigned short* __restrict__ csr, _Float16* __restrict__ out) {
  const int wave = threadIdx.x >> 6, lane = threadIdx.x & 63;
  const int node = blockIdx.x * 4 + wave;
  if (node >= NN) return;
  const int deg = cnt[node];
  const int n = min(deg, SLOT);
  const int base = node * SLOT;
  const int h = lane >> 5;          // half-wave id
  const int cb = (lane & 31) * 8;   // channel base (16B per lane)
  float a[8] = {0.f, 0.f, 0.f, 0.f, 0.f, 0.f, 0.f, 0.f};
  int i = h;
  for (; i + 14 < n; i += 16) {
    f16x8 v[8];
#pragma unroll
    for (int u = 0; u < 8; ++u) {
      int s = csr[base + i + 2 * u];
      v[u] = *(const f16x8*)&xin[s * DD + cb];
    }
#pragma unroll
    for (int j = 0; j < 8; ++j)
      a[j] += (((float)v[0][j] + (float)v[1][j]) + ((float)v[2][j] + (float)v[3][j])) +
              (((float)v[4][j] + (float)v[5][j]) + ((float)v[6][j] + (float)v[7][j]));
  }
  for (; i < n; i += 2) {
    int s = csr[base + i];
    f16x8 v = *(const f16x8*)&xin[s * DD + cb];
#pragma unroll
    for (int j = 0; j < 8; ++j) a[j] += (float)v[j];
  }
#pragma unroll
  for (int j = 0; j < 8; ++j) a[j] += __shfl_xor(a[j], 32);
  if (lane < 32) {
    float inv = 1.0f / fmaxf((float)deg, 1.0f);
    f16x8 r;
#pragma unroll
    for (int j = 0; j < 8; ++j) r[j] = (_Float16)(a[j] * inv);
    *(f16x8*)&out[node * DD + cb] = r;
  }
}

// ---------- fused SAGE GEMM via MFMA: 64x64 tile for occupancy ----------
// 628 tiles (157 row-blocks x 4 col-blocks) on 632 ids; each XCD gets a
// contiguous 79-tile chunk (T = xcd*79 + q) -> A-panel + W L2-resident.
// 4 waves, each 32x32 out (2x2 frags of 16x16x32), BK=64, dbuf LDS (32 KB
// total -> ~5 blocks/CU residency; cross-block overlap hides barrier drains).
// LDS linear [row][64] f16; chunk-XOR swizzle via pre-swizzled global source.
__global__ __launch_bounds__(256) void gemm_mfma_kernel(
    const _Float16* __restrict__ A1, const _Float16* __restrict__ A2,
    const _Float16* __restrict__ W1, const _Float16* __restrict__ W2,
    const float* __restrict__ bias, _Float16* __restrict__ out) {
  __shared__ _Float16 As[2][64 * 64];    // 8 KB per buffer
  __shared__ _Float16 Bs[2][64 * 64];
  const int xcd = blockIdx.x & 7;
  const int q = blockIdx.x >> 3;         // 0..78
  const int T = xcd * 79 + q;            // contiguous tile chunk per XCD
  if (T >= 628) return;                  // uniform exit (4 idle ids)
  const int rblk = T >> 2, cblk = T & 3;
  const int row0 = rblk * 64, col0 = cblk * 64;

  const int t = threadIdx.x;
  const int lane = t & 63;
  const int wid = t >> 6;
  const int wr = wid >> 1, wc = wid & 1; // wave quadrant: 32x32
  const int fr = lane & 15;              // frag row within 16
  const int fg = lane >> 4;              // frag k-group 0..3
  const int srl = lane >> 3;             // staging sub-row 0..7
  const int cj = lane & 7;               // staging chunk 0..7 (16B)

  f32x4 acc[2][2];
#pragma unroll
  for (int m = 0; m < 2; ++m)
#pragma unroll
    for (int n = 0; n < 2; ++n) {
      acc[m][n][0] = 0.f; acc[m][n][1] = 0.f;
      acc[m][n][2] = 0.f; acc[m][n][3] = 0.f;
    }

#define STAGE(B, S)                                                           \
  {                                                                           \
    const _Float16* Ap = ((S) < 4) ? A1 : A2;                                 \
    const _Float16* Wp = ((S) < 4) ? W1 : W2;                                 \
    const int k0 = ((S) & 3) * 64;                                            \
    const int gc = cj ^ srl;             /* row&7 == srl */                   \
    _Pragma("unroll") for (int j = 0; j < 2; ++j) {                           \
      int row = j * 32 + wid * 8 + srl;                                       \
      int gr = row0 + row; if (gr >= NN) gr = NN - 1;                         \
      gload16(Ap + (size_t)gr * DD + k0 + gc * 8,                             \
              &As[B][(j * 32 + wid * 8) * 64]);                               \
      gload16(Wp + (size_t)(col0 + row) * DD + k0 + gc * 8,                   \
              &Bs[B][(j * 32 + wid * 8) * 64]);                               \
    }                                                                         \
  }

  STAGE(0, 0);
  __syncthreads();

#pragma unroll
  for (int s = 0; s < 8; ++s) {
    const int b = s & 1;
    if (s < 7) STAGE(1 - b, s + 1);      // prefetch into other buffer
#pragma unroll
    for (int kk = 0; kk < 2; ++kk) {
      f16x8 af[2], bf[2];
#pragma unroll
      for (int m = 0; m < 2; ++m) {
        int row = wr * 32 + m * 16 + fr;
        int ch = (kk * 4 + fg) ^ (row & 7);
        af[m] = *(const f16x8*)&As[b][row * 64 + ch * 8];
      }
#pragma unroll
      for (int n = 0; n < 2; ++n) {
        int row = wc * 32 + n * 16 + fr;
        int ch = (kk * 4 + fg) ^ (row & 7);
        bf[n] = *(const f16x8*)&Bs[b][row * 64 + ch * 8];
      }
#pragma unroll
      for (int m = 0; m < 2; ++m)
#pragma unroll
        for (int n = 0; n < 2; ++n)
          acc[m][n] = __builtin_amdgcn_mfma_f32_16x16x32_f16(af[m], bf[n], acc[m][n], 0, 0, 0);
    }
    __syncthreads();                     // drains vmcnt+lgkm; flips buffers
  }
#undef STAGE

  // epilogue: D mapping col=lane&15, row=(lane>>4)*4+j  [m89]
  const int orow = row0 + wr * 32 + (lane >> 4) * 4;
  const int ocol = col0 + wc * 32 + fr;
#pragma unroll
  for (int m = 0; m < 2; ++m)
#pragma unroll
    for (int n = 0; n < 2; ++n) {
      int col = ocol + n * 16;
      float bv = bias[col];
#pragma unroll
      for (int j = 0; j < 4; ++j) {
        int row = orow + m * 16 + j;
        if (row < NN) {
          float v = acc[m][n][j] + bv;
          out[row * DD + col] = (_Float16)fmaxf(v, 0.f);
        }
      }
    }
}

// ---------- global add pool: chunked, register-accumulate, atomic flush ----------
__global__ __launch_bounds__(256) void pool_chunk_kernel(const _Float16* __restrict__ h2,
                                                         const int* __restrict__ batch,
                                                         float* __restrict__ pooled) {
  const int c = threadIdx.x;
  const int n0 = blockIdx.x * 16;        // 625*16 == NN
  float acc = 0.f;
  int g = batch[n0];
  for (int i = n0; i < n0 + 16; ++i) {
    int gi = batch[i];
    if (gi != g) {
      atomicAdd(&pooled[g * DD + c], acc);
      acc = 0.f;
      g = gi;
    }
    acc += (float)h2[i * DD + c];
  }
  atomicAdd(&pooled[g * DD + c], acc);
}

// ---------- classifier ----------
__global__ __launch_bounds__(256) void cls_kernel(const float* __restrict__ pooled,
                                                  const float* __restrict__ wc,
                                                  const float* __restrict__ bc,
                                                  float* __restrict__ out) {
  int t = blockIdx.x * 256 + threadIdx.x;
  if (t >= NG * DOUT) return;
  int g = t >> 4, j = t & 15;
  float s = bc[j];
  for (int k = 0; k < DD; k += 4) {
    float4 p = *(const float4*)&pooled[g * DD + k];
    float4 w = *(const float4*)&wc[j * DD + k];
    s += p.x * w.x + p.y * w.y + p.z * w.z + p.w * w.w;
  }
  out[t] = 1.0f / (1.0f + expf(-s));
}

extern "C" void kernel_launch(void* const* d_in, const int* in_sizes, int n_in,
                              void* d_out, int out_size, void* d_ws, size_t ws_size,
                              hipStream_t stream) {
  const float* x     = (const float*)d_in[0];
  const int*   ei    = (const int*)d_in[1];
  const int*   batch = (const int*)d_in[2];
  const float* w1_l  = (const float*)d_in[3];
  const float* b1_l  = (const float*)d_in[4];
  const float* w1_r  = (const float*)d_in[5];
  const float* w2_l  = (const float*)d_in[6];
  const float* b2_l  = (const float*)d_in[7];
  const float* w2_r  = (const float*)d_in[8];
  const float* w_cls = (const float*)d_in[9];
  const float* b_cls = (const float*)d_in[10];
  float* out = (float*)d_out;

  char* ws = (char*)d_ws;
  int*            cnt    = (int*)(ws + OFF_CNT);
  unsigned short* csr    = (unsigned short*)(ws + OFF_CSR);
  _Float16*       xh     = (_Float16*)(ws + OFF_XH);
  _Float16*       aggr   = (_Float16*)(ws + OFF_AGGR);
  _Float16*       h1     = (_Float16*)(ws + OFF_H1);
  _Float16*       h2     = (_Float16*)(ws + OFF_H2);
  _Float16*       wh     = (_Float16*)(ws + OFF_WH);
  float*          pooled = (float*)(ws + OFF_POOL);

  // 1. zero cnt + pooled
  init_kernel<<<64, 256, 0, stream>>>(cnt, pooled);

  // 2. padded-CSR fill (u16) + all fp16 casts (one dispatch)
  prep_kernel<<<NFB + NCB, 256, 0, stream>>>(ei, cnt, csr, x, w1_l, w1_r,
                                             w2_l, w2_r, xh, wh);

  const int agrid = (NN + 3) / 4;

  // 3-6. two SAGE layers
  aggregate_f16_kernel<<<agrid, 256, 0, stream>>>(xh, cnt, csr, aggr);
  gemm_mfma_kernel<<<632, 256, 0, stream>>>(aggr, xh, wh, wh + 65536, b1_l, h1);

  aggregate_f16_kernel<<<agrid, 256, 0, stream>>>(h1, cnt, csr, aggr);
  gemm_mfma_kernel<<<632, 256, 0, stream>>>(aggr, h1, wh + 2 * 65536, wh + 3 * 65536, b2_l, h2);

  // 7-8. pool + classifier
  pool_chunk_kernel<<<(NN + 15) / 16, 256, 0, stream>>>(h2, batch, pooled);
  cls_kernel<<<4, 256, 0, stream>>>(pooled, w_cls, b_cls, out);
}